// Round 9
// baseline (55.224 us; speedup 1.0000x reference)
//
#include <hip/hip_runtime.h>
#include <hip/hip_bf16.h>

#define BB 256
#define AA 512
#define DD 200
#define ADIM 600
#define NKC 4
#define KCH 150   // 600 / 4

// ws layout (floats):
//   X1     at 0        (256*600  = 153600)
//   parts  at 153600   (4*256*600 = 614400)
//   X2     at 768000   (256*600  = 153600)
//   logits at 921600   (256*512  = 131072)

// X1 = relu(obs @ W1 + b1). 128 blocks, 2 rows each, 320 threads.
__global__ __launch_bounds__(320) void k_x1(const float* __restrict__ obs,
                                            const float* __restrict__ W1,
                                            const float* __restrict__ b1,
                                            float* __restrict__ X1) {
  __shared__ __align__(16) float s_obs[2 * DD];
  const int rb = blockIdx.x * 2;  // first of 2 rows
  const int tid = threadIdx.x;
  if (tid < 100) {  // 2*200 floats = 100 float4, contiguous rows
    reinterpret_cast<float4*>(s_obs)[tid] =
        reinterpret_cast<const float4*>(obs + rb * DD)[tid];
  }
  __syncthreads();

  const int jp = tid;
  if (jp < 300) {
    const int j0 = 2 * jp;
    float a00 = 0.f, a01 = 0.f, a10 = 0.f, a11 = 0.f;
#pragma unroll 5
    for (int kq = 0; kq < 50; ++kq) {
      const float4 x0 = *reinterpret_cast<const float4*>(&s_obs[kq * 4]);
      const float4 x1 = *reinterpret_cast<const float4*>(&s_obs[DD + kq * 4]);
      const float* wb = W1 + (kq * 4) * ADIM + j0;
      const float2 w0 = *reinterpret_cast<const float2*>(wb);
      const float2 w1 = *reinterpret_cast<const float2*>(wb + ADIM);
      const float2 w2 = *reinterpret_cast<const float2*>(wb + 2 * ADIM);
      const float2 w3 = *reinterpret_cast<const float2*>(wb + 3 * ADIM);
      a00 = fmaf(x0.x, w0.x, a00); a01 = fmaf(x0.x, w0.y, a01);
      a10 = fmaf(x1.x, w0.x, a10); a11 = fmaf(x1.x, w0.y, a11);
      a00 = fmaf(x0.y, w1.x, a00); a01 = fmaf(x0.y, w1.y, a01);
      a10 = fmaf(x1.y, w1.x, a10); a11 = fmaf(x1.y, w1.y, a11);
      a00 = fmaf(x0.z, w2.x, a00); a01 = fmaf(x0.z, w2.y, a01);
      a10 = fmaf(x1.z, w2.x, a10); a11 = fmaf(x1.z, w2.y, a11);
      a00 = fmaf(x0.w, w3.x, a00); a01 = fmaf(x0.w, w3.y, a01);
      a10 = fmaf(x1.w, w3.x, a10); a11 = fmaf(x1.w, w3.y, a11);
    }
    const float2 bv = *reinterpret_cast<const float2*>(b1 + j0);
    float2 o0, o1;
    o0.x = fmaxf(a00 + bv.x, 0.f); o0.y = fmaxf(a01 + bv.y, 0.f);
    o1.x = fmaxf(a10 + bv.x, 0.f); o1.y = fmaxf(a11 + bv.y, 0.f);
    *reinterpret_cast<float2*>(X1 + rb * ADIM + j0) = o0;
    *reinterpret_cast<float2*>(X1 + (rb + 1) * ADIM + j0) = o1;
  }
}

// parts[kc][row][j] = X1[row][kc-chunk] @ W2[kc-chunk][j].
__global__ __launch_bounds__(640) void k_x2p(const float* __restrict__ X1,
                                             const float* __restrict__ W2,
                                             float* __restrict__ parts) {
  __shared__ __align__(16) float s_x1[4 * 152];  // 150 used, stride 152
  const int rg = blockIdx.x >> 2;
  const int kc = blockIdx.x & 3;
  const int tid = threadIdx.x;
  const int kbase = kc * KCH;

  for (int idx = tid; idx < 4 * KCH; idx += 640) {
    const int r = idx / KCH, c = idx % KCH;
    s_x1[r * 152 + c] = X1[(rg * 4 + r) * ADIM + kbase + c];
  }
  __syncthreads();

  const int j = tid;
  if (j < ADIM) {
    float acc0 = 0.f, acc1 = 0.f, acc2 = 0.f, acc3 = 0.f;
#pragma unroll 4
    for (int kq = 0; kq < 37; ++kq) {  // 37*4 = 148 of 150
      const int k4 = kq * 4;
      const float4 x0 = *reinterpret_cast<const float4*>(&s_x1[0 * 152 + k4]);
      const float4 x1 = *reinterpret_cast<const float4*>(&s_x1[1 * 152 + k4]);
      const float4 x2 = *reinterpret_cast<const float4*>(&s_x1[2 * 152 + k4]);
      const float4 x3 = *reinterpret_cast<const float4*>(&s_x1[3 * 152 + k4]);
      const float* wb = W2 + (size_t)(kbase + k4) * ADIM + j;
      const float w0 = wb[0];
      const float w1 = wb[ADIM];
      const float w2 = wb[2 * ADIM];
      const float w3 = wb[3 * ADIM];
      acc0 = fmaf(x0.x, w0, fmaf(x0.y, w1, fmaf(x0.z, w2, fmaf(x0.w, w3, acc0))));
      acc1 = fmaf(x1.x, w0, fmaf(x1.y, w1, fmaf(x1.z, w2, fmaf(x1.w, w3, acc1))));
      acc2 = fmaf(x2.x, w0, fmaf(x2.y, w1, fmaf(x2.z, w2, fmaf(x2.w, w3, acc2))));
      acc3 = fmaf(x3.x, w0, fmaf(x3.y, w1, fmaf(x3.z, w2, fmaf(x3.w, w3, acc3))));
    }
#pragma unroll
    for (int kk = 148; kk < KCH; ++kk) {
      const float w = W2[(size_t)(kbase + kk) * ADIM + j];
      acc0 = fmaf(s_x1[0 * 152 + kk], w, acc0);
      acc1 = fmaf(s_x1[1 * 152 + kk], w, acc1);
      acc2 = fmaf(s_x1[2 * 152 + kk], w, acc2);
      acc3 = fmaf(s_x1[3 * 152 + kk], w, acc3);
    }
    float* pb = parts + (size_t)kc * (BB * ADIM) + (rg * 4) * ADIM + j;
    pb[0] = acc0;
    pb[ADIM] = acc1;
    pb[2 * ADIM] = acc2;
    pb[3 * ADIM] = acc3;
  }
}

// Finalize X2 = b2 + sum_kc parts. One block per batch row.
__global__ __launch_bounds__(640) void k_x2(const float* __restrict__ parts,
                                            const float* __restrict__ b2,
                                            float* __restrict__ X2) {
  const int b = blockIdx.x;
  const int j = threadIdx.x;
  if (j < ADIM) {
    float v = b2[j];
#pragma unroll
    for (int kc = 0; kc < NKC; ++kc)
      v += parts[(size_t)kc * (BB * ADIM) + b * ADIM + j];
    X2[b * ADIM + j] = v;
  }
}

// In-row (16-lane) rotate-add (DPP), no LDS-pipe traffic.
template <int CTRL>
__device__ inline float rot_add(float x) {
  const int xi = __float_as_int(x);
  const int r = __builtin_amdgcn_update_dpp(0, xi, CTRL, 0xF, 0xF, false);
  return x + __int_as_float(r);
}

// One wave = 16 actions of one batch row; masked actions skipped (logit is
// exactly -1e31 in f32). Three passes (rel/ent/trip); each pass ISSUES all 16
// row-loads into a fully-unrolled register file first (loads pipeline in
// flight, one latency per pass instead of one per action), then reduces.
// pv accumulates across passes; one batched cross-row combine at the end.
#define GATHER_PASS(TBL, IDX, XSEG)                                            \
  {                                                                            \
    float4 rr[16];                                                             \
    _Pragma("unroll")                                                          \
    for (int i = 0; i < 16; ++i) {                                             \
      if ((bal >> i) & 1ULL) {                                                 \
        const int s = __builtin_amdgcn_readlane(IDX, i);                       \
        rr[i] = *reinterpret_cast<const float4*>(TBL + (size_t)s * DD + 4 * lc); \
      }                                                                        \
    }                                                                          \
    _Pragma("unroll")                                                          \
    for (int i = 0; i < 16; ++i) {                                             \
      if ((bal >> i) & 1ULL) {                                                 \
        float p = fmaf(rr[i].x, XSEG.x, fmaf(rr[i].y, XSEG.y,                  \
                   fmaf(rr[i].z, XSEG.z, rr[i].w * XSEG.w)));                  \
        p = rot_add<0x128>(p);                                                 \
        p = rot_add<0x124>(p);                                                 \
        p = rot_add<0x122>(p);                                                 \
        p = rot_add<0x121>(p);                                                 \
        pv = (q == i) ? p + pv : pv;                                           \
      }                                                                        \
    }                                                                          \
  }

__global__ __launch_bounds__(256, 4) void k_logits(
    const float* __restrict__ X2, const float* __restrict__ rel,
    const float* __restrict__ entt, const float* __restrict__ trip,
    const int* __restrict__ r_sp, const int* __restrict__ e_sp,
    const int* __restrict__ t_id, const int* __restrict__ amask,
    float* __restrict__ logits) {
  const int b = blockIdx.x >> 3;
  const int c = blockIdx.x & 7;
  const int w = threadIdx.x >> 6;
  const int lane = threadIdx.x & 63;
  const int base = b * AA + c * 64 + w * 16;  // first of this wave's 16 actions

  // X2 segments -> registers; lane l holds floats [4l,4l+4) of each segment.
  // Lanes >= 50 hold zeros so their (clamped, duplicated) row reads contribute 0.
  float4 xr = {0.f, 0.f, 0.f, 0.f}, xe = xr, xt = xr;
  if (lane < 50) {
    const float* x2row = X2 + b * ADIM;
    xr = *reinterpret_cast<const float4*>(x2row + 4 * lane);
    xe = *reinterpret_cast<const float4*>(x2row + DD + 4 * lane);
    xt = *reinterpret_cast<const float4*>(x2row + 2 * DD + 4 * lane);
  }

  // indices + mask for the wave's 16 actions, replicated across lanes
  const int q = lane & 15;
  const int idxR = r_sp[base + q];
  const int idxE = e_sp[base + q];
  const int idxT = t_id[base + q];
  const int mk = amask[base + q];
  const unsigned long long bal = __ballot(mk != 0);  // bit i (i<16): action i active

  const int lc = lane < 50 ? lane : 49;  // clamped float4 index within row

  float pv = 0.0f;  // lane (r,q): row-r partial of action q (summed over tables)

  GATHER_PASS(rel,  idxR, xr)
  GATHER_PASS(entt, idxE, xe)
  GATHER_PASS(trip, idxT, xt)

  // combine the 4 row-partials per action (batched: once per 16 actions)
  float t1 = pv + __shfl_xor(pv, 16);
  float t2 = t1 + __shfl_xor(t1, 32);  // all lanes: total for action (lane&15)

  if (lane < 16) {
    logits[base + lane] = mk ? t2 : -1e31f;
  }
}

__device__ inline float waveMax(float v) {
#pragma unroll
  for (int o = 32; o > 0; o >>= 1) v = fmaxf(v, __shfl_xor(v, o));
  return v;
}
__device__ inline float waveSum(float v) {
#pragma unroll
  for (int o = 32; o > 0; o >>= 1) v += __shfl_xor(v, o);
  return v;
}

__global__ __launch_bounds__(512) void k_soft(const float* __restrict__ logits,
                                              float* __restrict__ out_dist,
                                              float* __restrict__ out_ent) {
  __shared__ float s_red[8];
  const int b = blockIdx.x;
  const int tid = threadIdx.x;
  const float logit = logits[b * AA + tid];

  float m = waveMax(logit);
  if ((tid & 63) == 0) s_red[tid >> 6] = m;
  __syncthreads();
  float bm = s_red[0];
#pragma unroll
  for (int w = 1; w < 8; ++w) bm = fmaxf(bm, s_red[w]);
  __syncthreads();

  const float ev = __expf(logit - bm);
  float s = waveSum(ev);
  if ((tid & 63) == 0) s_red[tid >> 6] = s;
  __syncthreads();
  float bs = 0.0f;
#pragma unroll
  for (int w = 0; w < 8; ++w) bs += s_red[w];

  const float p = ev / bs;
  out_dist[b * AA + tid] = p;

  const float term = -p * __logf(p + 2.220446049250313e-16f);
  __syncthreads();
  float es = waveSum(term);
  if ((tid & 63) == 0) s_red[tid >> 6] = es;
  __syncthreads();
  if (tid == 0) {
    float etot = 0.0f;
#pragma unroll
    for (int w = 0; w < 8; ++w) etot += s_red[w];
    out_ent[b] = etot;
  }
}

extern "C" void kernel_launch(void* const* d_in, const int* in_sizes, int n_in,
                              void* d_out, int out_size, void* d_ws, size_t ws_size,
                              hipStream_t stream) {
  const float* obs  = (const float*)d_in[0];
  const float* W1   = (const float*)d_in[1];
  const float* b1   = (const float*)d_in[2];
  const float* W2   = (const float*)d_in[3];
  const float* b2   = (const float*)d_in[4];
  const float* rel  = (const float*)d_in[5];
  const float* entt = (const float*)d_in[6];
  const float* trip = (const float*)d_in[7];
  const int* r_sp   = (const int*)d_in[8];
  const int* e_sp   = (const int*)d_in[9];
  const int* t_id   = (const int*)d_in[10];
  const int* amask  = (const int*)d_in[11];

  float* ws = (float*)d_ws;
  float* X1     = ws;                         // 153600 floats
  float* parts  = ws + BB * ADIM;             // 614400 floats
  float* X2     = ws + BB * ADIM * (1 + NKC); // 153600 floats
  float* logits = ws + BB * ADIM * (2 + NKC); // 131072 floats

  float* out = (float*)d_out;

  k_x1<<<128, 320, 0, stream>>>(obs, W1, b1, X1);
  k_x2p<<<256, 640, 0, stream>>>(X1, W2, parts);
  k_x2<<<BB, 640, 0, stream>>>(parts, b2, X2);
  k_logits<<<BB * 8, 256, 0, stream>>>(X2, rel, entt, trip, r_sp, e_sp,
                                       t_id, amask, logits);
  k_soft<<<BB, 512, 0, stream>>>(logits, out, out + BB * AA);
}

// Round 10
// 51.719 us; speedup vs baseline: 1.0678x; 1.0678x over previous
//
#include <hip/hip_runtime.h>
#include <hip/hip_bf16.h>

#define BB 256
#define AA 512
#define DD 200
#define ADIM 600
#define NKC 4
#define KCH 150   // 600 / 4

// ws layout (floats):
//   X1     at 0        (256*600  = 153600)
//   parts  at 153600   (4*256*600 = 614400)
//   X2     at 768000   (256*600  = 153600)
//   logits at 921600   (256*512  = 131072)

// X1 = relu(obs @ W1 + b1). 128 blocks, 2 rows each, 320 threads.
__global__ __launch_bounds__(320) void k_x1(const float* __restrict__ obs,
                                            const float* __restrict__ W1,
                                            const float* __restrict__ b1,
                                            float* __restrict__ X1) {
  __shared__ __align__(16) float s_obs[2 * DD];
  const int rb = blockIdx.x * 2;  // first of 2 rows
  const int tid = threadIdx.x;
  if (tid < 100) {  // 2*200 floats = 100 float4, contiguous rows
    reinterpret_cast<float4*>(s_obs)[tid] =
        reinterpret_cast<const float4*>(obs + rb * DD)[tid];
  }
  __syncthreads();

  const int jp = tid;
  if (jp < 300) {
    const int j0 = 2 * jp;
    float a00 = 0.f, a01 = 0.f, a10 = 0.f, a11 = 0.f;
#pragma unroll 5
    for (int kq = 0; kq < 50; ++kq) {
      const float4 x0 = *reinterpret_cast<const float4*>(&s_obs[kq * 4]);
      const float4 x1 = *reinterpret_cast<const float4*>(&s_obs[DD + kq * 4]);
      const float* wb = W1 + (kq * 4) * ADIM + j0;
      const float2 w0 = *reinterpret_cast<const float2*>(wb);
      const float2 w1 = *reinterpret_cast<const float2*>(wb + ADIM);
      const float2 w2 = *reinterpret_cast<const float2*>(wb + 2 * ADIM);
      const float2 w3 = *reinterpret_cast<const float2*>(wb + 3 * ADIM);
      a00 = fmaf(x0.x, w0.x, a00); a01 = fmaf(x0.x, w0.y, a01);
      a10 = fmaf(x1.x, w0.x, a10); a11 = fmaf(x1.x, w0.y, a11);
      a00 = fmaf(x0.y, w1.x, a00); a01 = fmaf(x0.y, w1.y, a01);
      a10 = fmaf(x1.y, w1.x, a10); a11 = fmaf(x1.y, w1.y, a11);
      a00 = fmaf(x0.z, w2.x, a00); a01 = fmaf(x0.z, w2.y, a01);
      a10 = fmaf(x1.z, w2.x, a10); a11 = fmaf(x1.z, w2.y, a11);
      a00 = fmaf(x0.w, w3.x, a00); a01 = fmaf(x0.w, w3.y, a01);
      a10 = fmaf(x1.w, w3.x, a10); a11 = fmaf(x1.w, w3.y, a11);
    }
    const float2 bv = *reinterpret_cast<const float2*>(b1 + j0);
    float2 o0, o1;
    o0.x = fmaxf(a00 + bv.x, 0.f); o0.y = fmaxf(a01 + bv.y, 0.f);
    o1.x = fmaxf(a10 + bv.x, 0.f); o1.y = fmaxf(a11 + bv.y, 0.f);
    *reinterpret_cast<float2*>(X1 + rb * ADIM + j0) = o0;
    *reinterpret_cast<float2*>(X1 + (rb + 1) * ADIM + j0) = o1;
  }
}

// parts[kc][row][j] = X1[row][kc-chunk] @ W2[kc-chunk][j].
__global__ __launch_bounds__(640) void k_x2p(const float* __restrict__ X1,
                                             const float* __restrict__ W2,
                                             float* __restrict__ parts) {
  __shared__ __align__(16) float s_x1[4 * 152];  // 150 used, stride 152
  const int rg = blockIdx.x >> 2;
  const int kc = blockIdx.x & 3;
  const int tid = threadIdx.x;
  const int kbase = kc * KCH;

  for (int idx = tid; idx < 4 * KCH; idx += 640) {
    const int r = idx / KCH, c = idx % KCH;
    s_x1[r * 152 + c] = X1[(rg * 4 + r) * ADIM + kbase + c];
  }
  __syncthreads();

  const int j = tid;
  if (j < ADIM) {
    float acc0 = 0.f, acc1 = 0.f, acc2 = 0.f, acc3 = 0.f;
#pragma unroll 4
    for (int kq = 0; kq < 37; ++kq) {  // 37*4 = 148 of 150
      const int k4 = kq * 4;
      const float4 x0 = *reinterpret_cast<const float4*>(&s_x1[0 * 152 + k4]);
      const float4 x1 = *reinterpret_cast<const float4*>(&s_x1[1 * 152 + k4]);
      const float4 x2 = *reinterpret_cast<const float4*>(&s_x1[2 * 152 + k4]);
      const float4 x3 = *reinterpret_cast<const float4*>(&s_x1[3 * 152 + k4]);
      const float* wb = W2 + (size_t)(kbase + k4) * ADIM + j;
      const float w0 = wb[0];
      const float w1 = wb[ADIM];
      const float w2 = wb[2 * ADIM];
      const float w3 = wb[3 * ADIM];
      acc0 = fmaf(x0.x, w0, fmaf(x0.y, w1, fmaf(x0.z, w2, fmaf(x0.w, w3, acc0))));
      acc1 = fmaf(x1.x, w0, fmaf(x1.y, w1, fmaf(x1.z, w2, fmaf(x1.w, w3, acc1))));
      acc2 = fmaf(x2.x, w0, fmaf(x2.y, w1, fmaf(x2.z, w2, fmaf(x2.w, w3, acc2))));
      acc3 = fmaf(x3.x, w0, fmaf(x3.y, w1, fmaf(x3.z, w2, fmaf(x3.w, w3, acc3))));
    }
#pragma unroll
    for (int kk = 148; kk < KCH; ++kk) {
      const float w = W2[(size_t)(kbase + kk) * ADIM + j];
      acc0 = fmaf(s_x1[0 * 152 + kk], w, acc0);
      acc1 = fmaf(s_x1[1 * 152 + kk], w, acc1);
      acc2 = fmaf(s_x1[2 * 152 + kk], w, acc2);
      acc3 = fmaf(s_x1[3 * 152 + kk], w, acc3);
    }
    float* pb = parts + (size_t)kc * (BB * ADIM) + (rg * 4) * ADIM + j;
    pb[0] = acc0;
    pb[ADIM] = acc1;
    pb[2 * ADIM] = acc2;
    pb[3 * ADIM] = acc3;
  }
}

// Finalize X2 = b2 + sum_kc parts. One block per batch row.
__global__ __launch_bounds__(640) void k_x2(const float* __restrict__ parts,
                                            const float* __restrict__ b2,
                                            float* __restrict__ X2) {
  const int b = blockIdx.x;
  const int j = threadIdx.x;
  if (j < ADIM) {
    float v = b2[j];
#pragma unroll
    for (int kc = 0; kc < NKC; ++kc)
      v += parts[(size_t)kc * (BB * ADIM) + b * ADIM + j];
    X2[b * ADIM + j] = v;
  }
}

// In-row (16-lane) rotate-add (DPP), no LDS-pipe traffic.
template <int CTRL>
__device__ inline float rot_add(float x) {
  const int xi = __float_as_int(x);
  const int r = __builtin_amdgcn_update_dpp(0, xi, CTRL, 0xF, 0xF, false);
  return x + __int_as_float(r);
}

// One wave = 16 actions of one batch row; masked actions contribute exactly
// -1e31 (f32 rounding absorbs the score) so their gathers are skipped.
// Dense iteration over set mask bits (wave-uniform SALU ctz loop) with a
// depth-2 rotating load pipeline: action i+1's three 800B row-loads are in
// flight while action i is reduced, at full 6-waves/SIMD occupancy.
__global__ __launch_bounds__(256, 6) void k_logits(
    const float* __restrict__ X2, const float* __restrict__ rel,
    const float* __restrict__ entt, const float* __restrict__ trip,
    const int* __restrict__ r_sp, const int* __restrict__ e_sp,
    const int* __restrict__ t_id, const int* __restrict__ amask,
    float* __restrict__ logits) {
  const int b = blockIdx.x >> 3;
  const int c = blockIdx.x & 7;
  const int w = threadIdx.x >> 6;
  const int lane = threadIdx.x & 63;
  const int base = b * AA + c * 64 + w * 16;  // first of this wave's 16 actions

  // X2 segments -> registers; lane l holds floats [4l,4l+4) of each segment.
  // Lanes >= 50 hold zeros so their (clamped, duplicated) row reads contribute 0.
  float4 xr = {0.f, 0.f, 0.f, 0.f}, xe = xr, xt = xr;
  if (lane < 50) {
    const float* x2row = X2 + b * ADIM;
    xr = *reinterpret_cast<const float4*>(x2row + 4 * lane);
    xe = *reinterpret_cast<const float4*>(x2row + DD + 4 * lane);
    xt = *reinterpret_cast<const float4*>(x2row + 2 * DD + 4 * lane);
  }

  // indices + mask for the wave's 16 actions, replicated across lanes
  const int q = lane & 15;
  const int idxR = r_sp[base + q];
  const int idxE = e_sp[base + q];
  const int idxT = t_id[base + q];
  const int mk = amask[base + q];
  unsigned int mbits =
      (unsigned int)(__ballot(mk != 0) & 0xFFFFULL);  // bit i: action i active

  const int lc = lane < 50 ? lane : 49;  // clamped float4 index within row

  float pv = 0.0f;  // lane (r,q): row-r partial of action q

  if (mbits) {
    int i0 = __builtin_ctz(mbits);
    mbits &= mbits - 1;
    float4 vr = *reinterpret_cast<const float4*>(
        rel + (size_t)__builtin_amdgcn_readlane(idxR, i0) * DD + 4 * lc);
    float4 ve = *reinterpret_cast<const float4*>(
        entt + (size_t)__builtin_amdgcn_readlane(idxE, i0) * DD + 4 * lc);
    float4 vt = *reinterpret_cast<const float4*>(
        trip + (size_t)__builtin_amdgcn_readlane(idxT, i0) * DD + 4 * lc);

    while (mbits) {
      const int i1 = __builtin_ctz(mbits);
      mbits &= mbits - 1;
      // issue next action's loads (independent; stays in flight during reduce)
      const float4 nr = *reinterpret_cast<const float4*>(
          rel + (size_t)__builtin_amdgcn_readlane(idxR, i1) * DD + 4 * lc);
      const float4 ne = *reinterpret_cast<const float4*>(
          entt + (size_t)__builtin_amdgcn_readlane(idxE, i1) * DD + 4 * lc);
      const float4 nt = *reinterpret_cast<const float4*>(
          trip + (size_t)__builtin_amdgcn_readlane(idxT, i1) * DD + 4 * lc);

      // reduce current action
      float p = fmaf(vr.x, xr.x, fmaf(vr.y, xr.y, fmaf(vr.z, xr.z, vr.w * xr.w)));
      p = fmaf(ve.x, xe.x, fmaf(ve.y, xe.y, fmaf(ve.z, xe.z, fmaf(ve.w, xe.w, p))));
      p = fmaf(vt.x, xt.x, fmaf(vt.y, xt.y, fmaf(vt.z, xt.z, fmaf(vt.w, xt.w, p))));
      p = rot_add<0x128>(p);  // row_ror:8
      p = rot_add<0x124>(p);  // row_ror:4
      p = rot_add<0x122>(p);  // row_ror:2
      p = rot_add<0x121>(p);  // row_ror:1
      pv = (q == i0) ? p + pv : pv;

      vr = nr; ve = ne; vt = nt;
      i0 = i1;
    }

    // drain: reduce the last action
    float p = fmaf(vr.x, xr.x, fmaf(vr.y, xr.y, fmaf(vr.z, xr.z, vr.w * xr.w)));
    p = fmaf(ve.x, xe.x, fmaf(ve.y, xe.y, fmaf(ve.z, xe.z, fmaf(ve.w, xe.w, p))));
    p = fmaf(vt.x, xt.x, fmaf(vt.y, xt.y, fmaf(vt.z, xt.z, fmaf(vt.w, xt.w, p))));
    p = rot_add<0x128>(p);
    p = rot_add<0x124>(p);
    p = rot_add<0x122>(p);
    p = rot_add<0x121>(p);
    pv = (q == i0) ? p + pv : pv;
  }

  // combine the 4 row-partials per action (batched: once per 16 actions)
  const float u1 = pv + __shfl_xor(pv, 16);
  const float u2 = u1 + __shfl_xor(u1, 32);  // all lanes: total for action (lane&15)

  if (lane < 16) {
    logits[base + lane] = mk ? u2 : -1e31f;
  }
}

__device__ inline float waveMax(float v) {
#pragma unroll
  for (int o = 32; o > 0; o >>= 1) v = fmaxf(v, __shfl_xor(v, o));
  return v;
}
__device__ inline float waveSum(float v) {
#pragma unroll
  for (int o = 32; o > 0; o >>= 1) v += __shfl_xor(v, o);
  return v;
}

__global__ __launch_bounds__(512) void k_soft(const float* __restrict__ logits,
                                              float* __restrict__ out_dist,
                                              float* __restrict__ out_ent) {
  __shared__ float s_red[8];
  const int b = blockIdx.x;
  const int tid = threadIdx.x;
  const float logit = logits[b * AA + tid];

  float m = waveMax(logit);
  if ((tid & 63) == 0) s_red[tid >> 6] = m;
  __syncthreads();
  float bm = s_red[0];
#pragma unroll
  for (int w = 1; w < 8; ++w) bm = fmaxf(bm, s_red[w]);
  __syncthreads();

  const float ev = __expf(logit - bm);
  float s = waveSum(ev);
  if ((tid & 63) == 0) s_red[tid >> 6] = s;
  __syncthreads();
  float bs = 0.0f;
#pragma unroll
  for (int w = 0; w < 8; ++w) bs += s_red[w];

  const float p = ev / bs;
  out_dist[b * AA + tid] = p;

  const float term = -p * __logf(p + 2.220446049250313e-16f);
  __syncthreads();
  float es = waveSum(term);
  if ((tid & 63) == 0) s_red[tid >> 6] = es;
  __syncthreads();
  if (tid == 0) {
    float etot = 0.0f;
#pragma unroll
    for (int w = 0; w < 8; ++w) etot += s_red[w];
    out_ent[b] = etot;
  }
}

extern "C" void kernel_launch(void* const* d_in, const int* in_sizes, int n_in,
                              void* d_out, int out_size, void* d_ws, size_t ws_size,
                              hipStream_t stream) {
  const float* obs  = (const float*)d_in[0];
  const float* W1   = (const float*)d_in[1];
  const float* b1   = (const float*)d_in[2];
  const float* W2   = (const float*)d_in[3];
  const float* b2   = (const float*)d_in[4];
  const float* rel  = (const float*)d_in[5];
  const float* entt = (const float*)d_in[6];
  const float* trip = (const float*)d_in[7];
  const int* r_sp   = (const int*)d_in[8];
  const int* e_sp   = (const int*)d_in[9];
  const int* t_id   = (const int*)d_in[10];
  const int* amask  = (const int*)d_in[11];

  float* ws = (float*)d_ws;
  float* X1     = ws;                         // 153600 floats
  float* parts  = ws + BB * ADIM;             // 614400 floats
  float* X2     = ws + BB * ADIM * (1 + NKC); // 153600 floats
  float* logits = ws + BB * ADIM * (2 + NKC); // 131072 floats

  float* out = (float*)d_out;

  k_x1<<<128, 320, 0, stream>>>(obs, W1, b1, X1);
  k_x2p<<<256, 640, 0, stream>>>(X1, W2, parts);
  k_x2<<<BB, 640, 0, stream>>>(parts, b2, X2);
  k_logits<<<BB * 8, 256, 0, stream>>>(X2, rel, entt, trip, r_sp, e_sp,
                                       t_id, amask, logits);
  k_soft<<<BB, 512, 0, stream>>>(logits, out, out + BB * AA);
}